// Round 13
// baseline (1983.009 us; speedup 1.0000x reference)
//
#include <hip/hip_runtime.h>

// ---------------------------------------------------------------------------
// 2-layer LSTM LM, S=512 B=512 H=256 V=128 — Round 13: one-RT critical path.
// 256 blocks = 32 batch-groups x 8 col-blocks; weights VGPR/AGPR-resident.
// Evidence (R12 counters): agent-scope exchange does HBM-class RTs (~1-2us).
// So: exactly ONE serial RT per iter (h0 gather, no sentinel, stamp-verify
// retry); h1 gather issued early and verified after epi0 (RT hidden under
// 16 MFMAs + epilogue); h0 published at ~45% of the iter so peers' polls
// hit on arrival. Phases: P1 gather h0_{t-1} -> B1 -> P2 [issue h1 loads;
// MFMA L0(t)+L1a(t-1) over H0] -> B2 -> P3 epi0+pub0 -> verify+stage h1
// -> B3 -> P5 MFMA L1b+proj over H1 -> B4 -> P6 epi1+pub1+out.
// Exchange: per-layer stamped-u32 arrays, per-slice linear ([bg][slot][j][tid]),
// publisher stores tid-linear, gather instrs span contiguous 1KB. Slot
// parity (t-1)&1, want-stamp t for BOTH arrays; overwrite safety via
// program order (writer's P3/P6 of t+2 implies peers consumed t's words).
// h single fp16; c fp32 in regs; fp16 weights (the 2^-9 error floor).
// ---------------------------------------------------------------------------

#define S_ 512
#define B_ 512
#define H_ 256
#define V_ 128

typedef _Float16 f16;
typedef __attribute__((ext_vector_type(8))) _Float16 f16x8;
typedef __attribute__((ext_vector_type(4))) float f32x4;
typedef unsigned long long u64;
typedef unsigned u32;
typedef unsigned short u16;

// ws BYTE offsets
#define OFF_B0   0          // f16 frags [j8][w8][kk8][64][8]  = 512 KB (w_hh0)
#define OFF_B1   524288     // f16 frags [j8][w8][kk16][64][8] = 1 MB  (w_ih1|w_hh1)
#define OFF_BP   1572864    // f16 frags [j8][w8][64][8]       = 64 KB (W_out)
#define OFF_EX0  1638400    // h0: [bg32][slot2][j8][512] u32 = 1 MB
#define OFF_EX1  2686976    // h1: [bg32][slot2][j8][512] u32 = 1 MB

__device__ __forceinline__ float sigm(float z) { return 1.0f / (1.0f + __expf(-z)); }
__device__ __forceinline__ float tanh_fast(float z) {
  return 2.0f / (1.0f + __expf(-2.0f * z)) - 1.0f;
}

// ---------------------------------------------------------------------------
// prep: pack weights into per-(colblock,wave) fp16 MFMA B-fragment streams;
// zero both exchange arrays (stamp 0 never matches). B frag (16x16x32):
// lane l elem i -> B[k][n], k = kk*32+(l>>4)*8+i, n = l&15. Wave w of
// col-block j: gate=w>>1, half=w&1, hcol = j*32 + half*16 + n.
// ---------------------------------------------------------------------------
__global__ void prep_kernel(const float* __restrict__ w_hh0,
                            const float* __restrict__ w_ih1, const float* __restrict__ w_hh1,
                            const float* __restrict__ W_out, void* __restrict__ ws) {
  int idx = blockIdx.x * blockDim.x + threadIdx.x;
  f16* wsh = (f16*)ws;
  if (idx < 32768) {                                  // B0 (w_hh0)
    int j = idx >> 12, w = (idx >> 9) & 7, kk = (idx >> 6) & 7, lane = idx & 63;
    int gate = w >> 1, half = w & 1;
    int hcol = j * 32 + half * 16 + (lane & 15);
    int G = gate * H_ + hcol;
    int k0 = kk * 32 + (lane >> 4) * 8;
    f16x8 v;
    #pragma unroll
    for (int i = 0; i < 8; ++i) v[i] = (f16)w_hh0[G * H_ + k0 + i];
    *(f16x8*)(wsh + idx * 8) = v;
  } else if (idx < 32768 + 65536) {                   // B1 (K=512: w_ih1 | w_hh1)
    int t = idx - 32768;
    int j = t >> 13, w = (t >> 10) & 7, kk = (t >> 6) & 15, lane = t & 63;
    int gate = w >> 1, half = w & 1;
    int hcol = j * 32 + half * 16 + (lane & 15);
    int G = gate * H_ + hcol;
    int k0 = kk * 32 + (lane >> 4) * 8;
    const float* src = (k0 < H_) ? (w_ih1 + G * H_ + k0) : (w_hh1 + G * H_ + (k0 - H_));
    f16x8 v;
    #pragma unroll
    for (int i = 0; i < 8; ++i) v[i] = (f16)src[i];
    *(f16x8*)(wsh + 262144 + t * 8) = v;
  } else if (idx < 32768 + 65536 + 4096) {            // BP (W_out), kk = w
    int t = idx - (32768 + 65536);
    int j = t >> 9, w = (t >> 6) & 7, lane = t & 63;
    int vcol = j * 16 + (lane & 15);
    int k0 = w * 32 + (lane >> 4) * 8;
    f16x8 v;
    #pragma unroll
    for (int i = 0; i < 8; ++i) v[i] = (f16)W_out[vcol * H_ + k0 + i];
    *(f16x8*)(wsh + 786432 + t * 8) = v;
  } else if (idx < 102400 + 262144) {                 // zero EX0+EX1 (2 MB)
    ((u64*)((char*)ws + OFF_EX0))[idx - 102400] = 0ull;
  }
}

__device__ __forceinline__ u32 aload32(const u32* p) {
  return __hip_atomic_load((u32*)p, __ATOMIC_RELAXED, __HIP_MEMORY_SCOPE_AGENT);
}
__device__ __forceinline__ void astore32(u32* p, u32 v) {
  __hip_atomic_store(p, v, __ATOMIC_RELAXED, __HIP_MEMORY_SCOPE_AGENT);
}

// A-frag read, fragment-layout LDS: conflict-free (lane-consecutive 16B)
__device__ __forceinline__ f16x8 afrag(const f16* buf, int lane, int kk) {
  return *(const f16x8*)(buf + kk * 512 + lane * 8);
}

// stage 8 stamped u32 (lo16 = fp16 h) into frag-layout LDS tile w
__device__ __forceinline__ void stage8(u32* Hu, const u32* q, int w, int lane) {
  u32 p0 = (q[0] & 0xffffu) | (q[1] << 16);
  u32 p1 = (q[2] & 0xffffu) | (q[3] << 16);
  u32 p2 = (q[4] & 0xffffu) | (q[5] << 16);
  u32 p3 = (q[6] & 0xffffu) | (q[7] << 16);
  const int fi = (w * 512 + (lane >> 3) * 8 + ((lane & 7) >> 1) * 128 + 4 * (lane & 1)) >> 1;
  Hu[fi]      = p0; Hu[fi + 1]  = p1;
  Hu[fi + 32] = p2; Hu[fi + 33] = p3;     // rows +8 -> +64 f16 = +32 u32
}

__global__ __launch_bounds__(512, 2) void lstm_r13(const int* __restrict__ x,
                                                   const f16* __restrict__ wts,
                                                   u32* __restrict__ exh0,
                                                   u32* __restrict__ exh1,
                                                   const float* __restrict__ w_ih0,
                                                   const float* __restrict__ b_ih0,
                                                   const float* __restrict__ b_hh0,
                                                   const float* __restrict__ b_ih1,
                                                   const float* __restrict__ b_hh1,
                                                   const float* __restrict__ b_out,
                                                   float* __restrict__ out) {
  __shared__ __align__(16) f16 H0[4096], H1[4096];    // 16 KB, frag layout
  __shared__ __align__(16) float gsc0[4][16][33];
  __shared__ __align__(16) float gsc1[4][16][33];
  __shared__ __align__(16) float ppart[4][8][64];

  const int tid  = threadIdx.x;
  const int lane = tid & 63;
  const int w    = tid >> 6;            // wave 0..7: gate = w>>1, half = w&1
  const int bg   = blockIdx.x >> 3;     // batch group 0..31 (16 rows)
  const int j    = blockIdx.x & 7;      // col block 0..7 (32 h-cols)

  // ---- persistent weight fragments (VGPR/AGPR resident) ----
  f16x8 B0r[8], B1r[16], BPr;
  {
    const f16* p0 = wts + (size_t)(j * 8 + w) * 8 * 512 + lane * 8;
    #pragma unroll
    for (int kk = 0; kk < 8; ++kk) B0r[kk] = *(const f16x8*)(p0 + kk * 512);
    const f16* p1 = wts + 262144 + (size_t)(j * 8 + w) * 16 * 512 + lane * 8;
    #pragma unroll
    for (int kk = 0; kk < 16; ++kk) B1r[kk] = *(const f16x8*)(p1 + kk * 512);
    BPr = *(const f16x8*)(wts + 786432 + (size_t)(j * 8 + w) * 512 + lane * 8);
  }

  // ---- per-thread epilogue constants: (erow = tid>>5, ecol = tid&31) ----
  const int erow = tid >> 5, ecol = tid & 31;
  const int hcol = j * 32 + ecol;
  const int browg = bg * 16 + erow;
  float wxv[4], bz0v[4], bz1v[4];
  #pragma unroll
  for (int g = 0; g < 4; ++g) {
    int G = g * H_ + hcol;
    wxv[g]  = w_ih0[G];
    bz0v[g] = b_ih0[G] + b_hh0[G];
    bz1v[g] = b_ih1[G] + b_hh1[G];
  }
  const float bo = (tid < 256) ? b_out[j * 16 + (tid & 15)] : 0.f;

  u32* ex0G = exh0 + (size_t)bg * 8192;   // [slot2][j8][512]
  u32* ex1G = exh1 + (size_t)bg * 8192;

  // own-tile LDS position (f16 idx) for (erow, ecol) in frag layout, tile j
  const int fij = j * 512 + (erow + 16 * (ecol >> 3)) * 8 + (ecol & 7);

  float c0 = 0.f, c1 = 0.f;

  // zero LDS h buffers (h0_{-1} = h1_{-1} = 0)
  ((u64*)H0)[tid] = 0ull; ((u64*)H0)[tid + 512] = 0ull;
  ((u64*)H1)[tid] = 0ull; ((u64*)H1)[tid + 512] = 0ull;
  __syncthreads();

  #pragma unroll 1
  for (int t = 0; t <= S_ + 1; ++t) {
    float xf = (t < S_) ? (float)x[t * B_ + browg] : 0.f;
    const u32 want = ((u32)t & 0xffffu) << 16;
    const bool g0 = (t >= 1) && (t <= S_) && (w != j);
    const bool g1 = (t >= 2) && (t <= S_ + 1) && (w != j);

    // ---- P1: gather h0_{t-1} (the ONE serial RT), stamp-verify retry ----
    if (g0) {
      const u32* sb = ex0G + ((t - 1) & 1) * 4096 + w * 512;
      u32 q[8];
      for (;;) {
        #pragma unroll
        for (int i = 0; i < 4; ++i) q[i] = aload32(sb + 4 * lane + i);
        #pragma unroll
        for (int i = 0; i < 4; ++i) q[4 + i] = aload32(sb + 256 + 4 * lane + i);
        u32 bad = 0;
        #pragma unroll
        for (int i = 0; i < 8; ++i) bad |= (q[i] ^ want);
        if (!__any((int)((bad & 0xffff0000u) != 0))) break;
        __builtin_amdgcn_s_sleep(1);
      }
      stage8((u32*)H0, q, w, lane);
    }
    __syncthreads();                                  // B1

    // ---- P2: issue h1 loads early; MFMA L0(t) + L1a(t-1) over H0 ----
    u32 r[8];
    const u32* sb1 = ex1G + ((t - 1) & 1) * 4096 + w * 512;
    if (g1) {
      #pragma unroll
      for (int i = 0; i < 4; ++i) r[i] = aload32(sb1 + 4 * lane + i);
      #pragma unroll
      for (int i = 0; i < 4; ++i) r[4 + i] = aload32(sb1 + 256 + 4 * lane + i);
    }
    f32x4 acc0 = {0.f, 0.f, 0.f, 0.f};
    f32x4 acc1 = {0.f, 0.f, 0.f, 0.f};
    #pragma unroll
    for (int kk = 0; kk < 8; ++kk) {
      f16x8 ah = afrag(H0, lane, kk);
      acc0 = __builtin_amdgcn_mfma_f32_16x16x32_f16(ah, B0r[kk], acc0, 0, 0, 0);
      acc1 = __builtin_amdgcn_mfma_f32_16x16x32_f16(ah, B1r[kk], acc1, 0, 0, 0);
    }
    {
      const int gate = w >> 1, half = w & 1;
      const int c16 = lane & 15, r0 = (lane >> 4) * 4;
      #pragma unroll
      for (int rr = 0; rr < 4; ++rr) gsc0[gate][r0 + rr][half * 16 + c16] = acc0[rr];
    }
    __syncthreads();                                  // B2

    // ---- P3: epi0 -> publish h0_t EARLY; then verify+stage h1_{t-2} ----
    if (t < S_) {
      float gi = gsc0[0][erow][ecol] + xf * wxv[0] + bz0v[0];
      float gf = gsc0[1][erow][ecol] + xf * wxv[1] + bz0v[1];
      float gg = gsc0[2][erow][ecol] + xf * wxv[2] + bz0v[2];
      float go = gsc0[3][erow][ecol] + xf * wxv[3] + bz0v[3];
      c0 = sigm(gf) * c0 + sigm(gi) * tanh_fast(gg);
      float h0f = sigm(go) * tanh_fast(c0);
      union { f16 h; u16 u; } ha; ha.h = (f16)h0f;
      astore32(ex0G + (t & 1) * 4096 + j * 512 + tid,
               ((((u32)(t + 1)) & 0xffffu) << 16) | (u32)ha.u);
      H0[fij] = ha.h;                   // own tile for next iter's L0/L1a
    }
    if (g1) {
      for (;;) {
        u32 bad = 0;
        #pragma unroll
        for (int i = 0; i < 8; ++i) bad |= (r[i] ^ want);
        if (!__any((int)((bad & 0xffff0000u) != 0))) break;
        __builtin_amdgcn_s_sleep(1);
        #pragma unroll
        for (int i = 0; i < 4; ++i) r[i] = aload32(sb1 + 4 * lane + i);
        #pragma unroll
        for (int i = 0; i < 4; ++i) r[4 + i] = aload32(sb1 + 256 + 4 * lane + i);
      }
      stage8((u32*)H1, r, w, lane);
    }
    __syncthreads();                                  // B3

    // ---- P5: MFMA L1b(t-1) + proj(t-2) over H1 ----
    f32x4 ap = {0.f, 0.f, 0.f, 0.f};
    #pragma unroll
    for (int kk = 0; kk < 8; ++kk) {
      f16x8 ah = afrag(H1, lane, kk);
      acc1 = __builtin_amdgcn_mfma_f32_16x16x32_f16(ah, B1r[kk + 8], acc1, 0, 0, 0);
    }
    ap = __builtin_amdgcn_mfma_f32_16x16x32_f16(afrag(H1, lane, w), BPr, ap, 0, 0, 0);
    {
      const int gate = w >> 1, half = w & 1;
      const int c16 = lane & 15, r0 = (lane >> 4) * 4;
      #pragma unroll
      for (int rr = 0; rr < 4; ++rr) {
        gsc1[gate][r0 + rr][half * 16 + c16] = acc1[rr];
        ppart[rr][w][lane] = ap[rr];
      }
    }
    __syncthreads();                                  // B4

    // ---- P6: epi1 -> publish h1_{t-1}; out store t-2 ----
    if (t >= 1 && t <= S_) {
      float gi = gsc1[0][erow][ecol] + bz1v[0];
      float gf = gsc1[1][erow][ecol] + bz1v[1];
      float gg = gsc1[2][erow][ecol] + bz1v[2];
      float go = gsc1[3][erow][ecol] + bz1v[3];
      c1 = sigm(gf) * c1 + sigm(gi) * tanh_fast(gg);
      float h1f = sigm(go) * tanh_fast(c1);
      union { f16 h; u16 u; } hb; hb.h = (f16)h1f;
      astore32(ex1G + (t & 1) * 4096 + j * 512 + tid,
               ((((u32)(t + 1)) & 0xffffu) << 16) | (u32)hb.u);
      H1[fij] = hb.h;                   // own tile for next iter's L1b/proj
    }
    if (t >= 2 && tid < 256) {
      int prow = tid >> 4, pvc = tid & 15;
      int plane = (prow >> 2) * 16 + pvc, preg = prow & 3;
      float s = bo;
      #pragma unroll
      for (int ww = 0; ww < 8; ++ww) s += ppart[preg][ww][plane];
      out[((size_t)((t - 2) * B_ + bg * 16 + prow)) * V_ + j * 16 + pvc] = s;
    }
  }
}

extern "C" void kernel_launch(void* const* d_in, const int* in_sizes, int n_in,
                              void* d_out, int out_size, void* d_ws, size_t ws_size,
                              hipStream_t stream) {
  const int*   x     = (const int*)d_in[0];
  const float* w_ih0 = (const float*)d_in[1];
  const float* w_hh0 = (const float*)d_in[2];
  const float* b_ih0 = (const float*)d_in[3];
  const float* b_hh0 = (const float*)d_in[4];
  const float* w_ih1 = (const float*)d_in[5];
  const float* w_hh1 = (const float*)d_in[6];
  const float* b_ih1 = (const float*)d_in[7];
  const float* b_hh1 = (const float*)d_in[8];
  const float* W_out = (const float*)d_in[9];
  const float* b_out = (const float*)d_in[10];

  // prep threads: 102400 + 262144 = 364544 = 1424 * 256
  prep_kernel<<<1424, 256, 0, stream>>>(w_hh0, w_ih1, w_hh1, W_out, d_ws);

  lstm_r13<<<256, 512, 0, stream>>>(x, (const f16*)d_ws,
                                    (u32*)((char*)d_ws + OFF_EX0),
                                    (u32*)((char*)d_ws + OFF_EX1),
                                    w_ih0, b_ih0, b_hh0, b_ih1, b_hh1, b_out,
                                    (float*)d_out);
}